// Round 2
// baseline (454.314 us; speedup 1.0000x reference)
//
#include <hip/hip_runtime.h>

// B=32, K=9, C=3, H=W=256, N_INPUTS=2 (im has 6 channels, last 3 used).
#define BB 32
#define KK 9
#define CC 3
#define HH 256
#define WW 256
#define HW (HH * WW)          // 65536
#define TW 32
#define TH 8
#define HALO_W (TW + 2)       // 34
#define HALO_H (TH + 2)       // 10
#define HALO_N (HALO_W * HALO_H)  // 340

// d_out layout (floats), reference return order:
//  o0 pred [B,3,H,W] | o1 mask_f [B,9,H,W] | o2 dis_f [B,1,H,W] | o3 attn |
//  o4 mask_b [B,9,H,W] | o5 dis_b | o6 1-attn
#define SZ_P ((size_t)BB * CC * HW)
#define SZ_M ((size_t)BB * KK * HW)
#define SZ_S ((size_t)BB * HW)

__device__ __forceinline__ float clamp01(float v) {
  return fminf(fmaxf(v, 0.f), 1.f);
}

__global__ __launch_bounds__(256) void binet_fused_kernel(
    const float* __restrict__ im_f, const float* __restrict__ im_b,
    const float* __restrict__ gt_f, const float* __restrict__ gt_b,
    float* __restrict__ out) {
  __shared__ float sf[HALO_H][HALO_W];   // seg_f on halo tile
  __shared__ float sb[HALO_H][HALO_W];   // seg_b on halo tile

  const int tx = threadIdx.x;            // 0..31
  const int ty = threadIdx.y;            // 0..7
  const int tid = ty * TW + tx;
  const int x0 = blockIdx.x * TW;
  const int y0 = blockIdx.y * TH;
  const int b  = blockIdx.z;

  const float* gf = gt_f + (size_t)b * KK * HW;
  const float* gb = gt_b + (size_t)b * KK * HW;

  // ---- Phase 1: seg over the (TH+2)x(TW+2) halo tile ----
  for (int i = tid; i < HALO_N; i += TW * TH) {
    int hy = i / HALO_W;
    int hx = i - hy * HALO_W;
    int y = y0 + hy - 1;
    int x = x0 + hx - 1;
    float segf = 0.f, segb = 0.f;
    if (y >= 0 && y < HH && x >= 0 && x < WW) {
#pragma unroll
      for (int k = 0; k < KK; ++k) {
        int yy = y + (k / 3) - 1;
        int xx = x + (k % 3) - 1;
        if (yy >= 0 && yy < HH && xx >= 0 && xx < WW) {
          int off = k * HW + (yy << 8) + xx;
          segf += gf[off];
          segb += gb[off];
        }
      }
    }
    sf[hy][hx] = segf;
    sb[hy][hx] = segb;
  }
  __syncthreads();

  // ---- Phase 2: per center pixel ----
  const int x = x0 + tx;
  const int y = y0 + ty;
  const int p = (y << 8) + x;
  const size_t idx = (size_t)b * HW + p;

  float seg_fc = sf[ty + 1][tx + 1];
  float seg_bc = sb[ty + 1][tx + 1];

  // scalar outputs
  float sfc = fminf(seg_fc, 1.f);
  float sbc = fminf(seg_bc, 1.f);
  float attn = (sfc + 1e-5f) / (sfc + sbc + 2e-5f);
  out[SZ_P + SZ_M + idx]                     = clamp01(seg_fc - 1.f);  // o2
  out[SZ_P + SZ_M + SZ_S + idx]              = attn;                   // o3
  out[SZ_P + 2 * SZ_M + 2 * SZ_S + idx]      = clamp01(seg_bc - 1.f);  // o5
  out[SZ_P + 2 * SZ_M + 3 * SZ_S + idx]      = 1.f - attn;             // o6

  // mask pass-through copies (center values are L1-hot from phase 1)
  float* omf = out + SZ_P + (size_t)b * KK * HW + p;
  float* omb = out + SZ_P + SZ_M + 2 * SZ_S + (size_t)b * KK * HW + p;
#pragma unroll
  for (int k = 0; k < KK; ++k) {
    omf[(size_t)k * HW] = gf[k * HW + p];
    omb[(size_t)k * HW] = gb[k * HW + p];
  }

  // pred: 9-tap gather with appear from LDS seg
  const float* imf = im_f + ((size_t)b * 6 + 3) * HW;
  const float* imb = im_b + ((size_t)b * 6 + 3) * HW;

  float pf0 = 0.f, pf1 = 0.f, pf2 = 0.f;
  float pb0 = 0.f, pb1 = 0.f, pb2 = 0.f;
#pragma unroll
  for (int k = 0; k < KK; ++k) {
    int dy = (k / 3) - 1;
    int dx = (k % 3) - 1;
    int yy = y + dy;
    int xx = x + dx;
    if (yy >= 0 && yy < HH && xx >= 0 && xx < WW) {
      int q = (yy << 8) + xx;
      float af = clamp01(2.f - sf[ty + 1 + dy][tx + 1 + dx]);
      float wf = af * gf[k * HW + q];
      pf0 = fmaf(wf, imf[q], pf0);
      pf1 = fmaf(wf, imf[HW + q], pf1);
      pf2 = fmaf(wf, imf[2 * HW + q], pf2);
      float ab = clamp01(2.f - sb[ty + 1 + dy][tx + 1 + dx]);
      float wb = ab * gb[k * HW + q];
      pb0 = fmaf(wb, imb[q], pb0);
      pb1 = fmaf(wb, imb[HW + q], pb1);
      pb2 = fmaf(wb, imb[2 * HW + q], pb2);
    }
  }

  float at2 = 1.f - attn;
  size_t pbase = (size_t)b * CC * HW + p;
  out[pbase]          = fmaf(attn, pf0, at2 * pb0);
  out[pbase + HW]     = fmaf(attn, pf1, at2 * pb1);
  out[pbase + 2 * HW] = fmaf(attn, pf2, at2 * pb2);
}

extern "C" void kernel_launch(void* const* d_in, const int* in_sizes, int n_in,
                              void* d_out, int out_size, void* d_ws, size_t ws_size,
                              hipStream_t stream) {
  const float* im_f = (const float*)d_in[0];
  const float* im_b = (const float*)d_in[1];
  // d_in[2] = ones (identity), d_in[5] = one-hot m_kernel (hardcoded shifts)
  const float* gt_f = (const float*)d_in[3];
  const float* gt_b = (const float*)d_in[4];
  float* out = (float*)d_out;

  dim3 block(TW, TH);
  dim3 grid(WW / TW, HH / TH, BB);
  binet_fused_kernel<<<grid, block, 0, stream>>>(im_f, im_b, gt_f, gt_b, out);
}